// Round 19
// baseline (10272.714 us; speedup 1.0000x reference)
//
#include <hip/hip_runtime.h>

typedef unsigned short u16;
typedef _Float16 f16_t;
typedef f16_t f16x8 __attribute__((ext_vector_type(8)));
typedef float f32x4 __attribute__((ext_vector_type(4)));
typedef unsigned u32x4 __attribute__((ext_vector_type(4)));

#define T_STEPS 256
#define IN_DIM  5
#define NBLK    512

// d_ws byte layout:
//   WS_W    @ 0       : weight frags [32 slice][50 frag][64 lane][16B] = 1,638,400
//   WS_BIAS @ 1638400 : f32 bias0[1024], bias1[1024]                    (8 KB)
//   WS_FC   @ 1646592 : fc_w B-frags [8 ks][64 lane][16B]               (8 KB)
//   WS_GX   @ 1654784 : u16 gx[which(2)*2+parity][64 grp][8 sub][64 row][32 col]
//                       4 buffers x 2 MB = 8 MB
//   WS_CNT  @ 10043392: u32 flags[64 grp][8 sub] (zeroed each launch by prep)
#define WS_BIAS 1638400
#define WS_FC   1646592
#define WS_GX   1654784
#define GXS2    1048576                 // u16 elements per (which,parity) buffer
#define WS_CNT  (WS_GX + 8388608)

__device__ __forceinline__ float sigf(float x)  { return 1.0f / (1.0f + __expf(-x)); }
__device__ __forceinline__ float tanh_f(float x){ return 1.0f - 2.0f / (__expf(2.0f * x) + 1.0f); }

__global__ void prep_kernel(const float* __restrict__ wih0, const float* __restrict__ whh0,
                            const float* __restrict__ wih1, const float* __restrict__ whh1,
                            const float* __restrict__ bih0, const float* __restrict__ bhh0,
                            const float* __restrict__ bih1, const float* __restrict__ bhh1,
                            const float* __restrict__ fcw,
                            u16* __restrict__ wsw, float* __restrict__ biases,
                            u16* __restrict__ wsfc, unsigned* __restrict__ cnt)
{
    int j = blockIdx.x * blockDim.x + threadIdx.x;
    if (j < 102400) {
        // j = (slice*50 + f)*64 + lane ; slice = sub*4 + wv  (32 slices)
        int slice = j / 3200;
        int rem   = j - slice * 3200;
        int f     = rem >> 6;           // 0..49
        int lane  = rem & 63;
        int sub = slice >> 2, wv = slice & 3;
        int lrow = lane & 15;
        int kp = (lane >> 4) * 8;
        int nt, ks; bool g0;
        if (f < 18) { g0 = true;  nt = f / 9;  ks = f - nt * 9; }
        else        { int ff = f - 18; g0 = false; nt = ff >> 4; ks = ff & 15; }
        int wr = (nt * 2 + (lrow >> 3)) * 256 + sub * 32 + wv * 8 + (lrow & 7);
        u16 tmp[8];
#pragma unroll
        for (int e = 0; e < 8; ++e) {
            int k = kp + e;
            float v;
            if (g0) {
                v = (ks < 8) ? whh0[wr * 256 + ks * 32 + k]
                             : (k < IN_DIM ? wih0[wr * IN_DIM + k] : 0.0f);
            } else {
                v = (ks < 8) ? wih1[wr * 256 + ks * 32 + k]
                             : whh1[wr * 256 + (ks - 8) * 32 + k];
            }
            tmp[e] = __builtin_bit_cast(u16, (f16_t)v);
        }
        *(uint4*)(wsw + (size_t)j * 8) = *(uint4*)tmp;
    } else if (j < 103424) {
        int i = j - 102400;
        biases[i] = bih0[i] + bhh0[i];
    } else if (j < 104448) {
        int i = j - 103424;
        biases[1024 + i] = bih1[i] + bhh1[i];
    } else if (j < 104960) {
        // fc_w as MFMA B-fragments: B[k][n] = (n==0) ? fcw[k] : 0
        int q = j - 104448;
        int ks = q >> 6, lane = q & 63;
        u16 tmp[8];
#pragma unroll
        for (int e = 0; e < 8; ++e) {
            float v = ((lane & 15) == 0) ? fcw[ks * 32 + (lane >> 4) * 8 + e] : 0.0f;
            tmp[e] = __builtin_bit_cast(u16, (f16_t)v);
        }
        *(uint4*)(wsfc + (size_t)q * 8) = *(uint4*)tmp;
    } else if (j < 107008) {
        cnt[j - 104960] = 0u;
    }
}

__global__ __launch_bounds__(256, 2) void lstm_fused(
    const float* __restrict__ x, const u16* __restrict__ wsw,
    const float* __restrict__ biases, const u16* __restrict__ wsfc,
    const float* __restrict__ fcb_g, float* __restrict__ out,
    u16* __restrict__ gxbase, unsigned* __restrict__ cnt)
{
    extern __shared__ char smem[];
    char* h0b  = smem;                 // [64 rows][512B] fp16, XOR-swizzled
    char* h1b  = smem + 32768;
    char* xbb  = smem + 65536;         // [64 rows][64B]
    char* wfcL = smem + 69632;         // fc_w frags [8 ks][64 lane][16B] = 8KB; total 77824

    const int tid  = threadIdx.x;
    const int wv   = tid >> 6;
    const int lane = tid & 63;
    const int lrow = lane & 15;
    const int lkg  = lane >> 4;
    const int hf   = lrow >> 3;        // gate-half: 0 -> (i,g), 1 -> (f,o)
    const int cj   = lrow & 7;
    // block -> (grp, sub): co-resident pair (b, b+256) lands in DIFFERENT groups
    // (mutual phase cover); group members share blockIdx%8 -> same XCD (perf only).
    const int bi   = blockIdx.x;
    const int grp  = (bi & 31) | ((bi >> 8) << 5);   // 0..63
    const int sub  = (bi >> 5) & 7;                  // 0..7
    const int r0   = grp * 64;                        // 64 batch rows per group
    const int aswz = (lrow & 7) << 4;
    const int xswz = (lrow & 3) << 4;

    // ---- resident weights: 50 shard frags = 200 AGPRs/lane ----
    f16x8 w0[2][9], w1[2][16];
    const u16* wbase = wsw + (size_t)(sub * 4 + wv) * 25600;
#pragma unroll
    for (int nt = 0; nt < 2; ++nt)
#pragma unroll
        for (int ks = 0; ks < 9; ++ks) {
            w0[nt][ks] = *(const f16x8*)(wbase + (nt * 9 + ks) * 512 + lane * 8);
            asm volatile("" : "+a"(w0[nt][ks]));
            __builtin_amdgcn_sched_barrier(0);
        }
#pragma unroll
    for (int nt = 0; nt < 2; ++nt)
#pragma unroll
        for (int ks = 0; ks < 16; ++ks) {
            w1[nt][ks] = *(const f16x8*)(wbase + (18 + nt * 16 + ks) * 512 + lane * 8);
            asm volatile("" : "+a"(w1[nt][ks]));
            __builtin_amdgcn_sched_barrier(0);
        }

    float b0[2], b1[2];
#pragma unroll
    for (int nt = 0; nt < 2; ++nt) {
        int wr = (nt * 2 + hf) * 256 + sub * 32 + wv * 8 + cj;
        b0[nt] = biases[wr];
        b1[nt] = biases[1024 + wr];
    }
    const float fcb = fcb_g[0];

    unsigned* f    = cnt + grp * 8;
    unsigned* fme  = f + sub;

    auto gxr = [&](int which, int parity) -> u16* {
        return gxbase + (size_t)(which * 2 + parity) * GXS2 + grp * 16384;
    };

    // zero all LDS, then fill fc frags + x0
    for (int i = tid; i < 77824 / 4; i += 256) ((unsigned*)smem)[i] = 0u;
    __syncthreads();
    for (int i = tid; i < 512; i += 256)
        *(uint4*)(wfcL + i * 16) = *(const uint4*)(wsfc + (size_t)i * 8);
    {
        int i0 = tid, i1 = tid + 256;
        if (i0 < 320) { int row = i0 / 5, k = i0 - row * 5;
            float v = x[((size_t)(r0 + row) * T_STEPS + 0) * IN_DIM + k];
            *(u16*)(xbb + row * 64 + ((2 * k) ^ ((row & 3) << 4))) = __builtin_bit_cast(u16, (f16_t)v); }
        if (i1 < 320) { int row = i1 / 5, k = i1 - row * 5;
            float v = x[((size_t)(r0 + row) * T_STEPS + 0) * IN_DIM + k];
            *(u16*)(xbb + row * 64 + ((2 * k) ^ ((row & 3) << 4))) = __builtin_bit_cast(u16, (f16_t)v); }
    }
    __syncthreads();

    float c0[4][2] = {}, c1[4][2] = {};

    // PUB: pack a full 8-col row (16B) per cluster via shfl_xor 1/2/4 butterfly,
    // then ONE global_store_dwordx4 sc0 sc1 from lanes cj in {0,1}.
    auto PUB = [&](u16* gxw, int mt, unsigned hv) {
        unsigned sh = __shfl_xor(hv, 1);
        const int rsel = cj & 1;
        unsigned w01;
        if (rsel) w01 = (sh >> 16) | (hv & 0xffff0000u);
        else      w01 = (hv & 0xffffu) | (sh << 16);
        unsigned p2 = __shfl_xor(w01, 2);
        unsigned lo4, hi4;
        if (cj & 2) { lo4 = p2;  hi4 = w01; }
        else        { lo4 = w01; hi4 = p2;  }
        unsigned q0 = __shfl_xor(lo4, 4), q1 = __shfl_xor(hi4, 4);
        u32x4 full;
        if (cj & 4) { full[0] = q0;  full[1] = q1;  full[2] = lo4; full[3] = hi4; }
        else        { full[0] = lo4; full[1] = hi4; full[2] = q0;  full[3] = q1;  }
        if (cj < 2) {
            int row = mt * 16 + lkg * 4 + hf * 2 + rsel;
            char* ap = (char*)gxw + sub * 4096 + row * 64 + wv * 16;
            asm volatile("global_store_dwordx4 %0, %1, off sc0 sc1"
                         :: "v"(ap), "v"(full) : "memory");
        }
    };

    auto GEMM0x = [&](float (&cs)[4][2], u16* gxw) {
#pragma unroll
        for (int mt = 0; mt < 4; ++mt) {
            f32x4 a0 = {}, a1 = {};
            const int arow = mt * 16 + lrow;
#pragma unroll
            for (int ks = 0; ks < 8; ++ks) {
                f16x8 a = *(const f16x8*)(h0b + arow * 512 + ((ks * 64 + lkg * 16) ^ aswz));
                a0 = __builtin_amdgcn_mfma_f32_16x16x32_f16(a, w0[0][ks], a0, 0, 0, 0);
                a1 = __builtin_amdgcn_mfma_f32_16x16x32_f16(a, w0[1][ks], a1, 0, 0, 0);
            }
            {
                f16x8 a = *(const f16x8*)(xbb + arow * 64 + ((lkg * 16) ^ xswz));
                a0 = __builtin_amdgcn_mfma_f32_16x16x32_f16(a, w0[0][8], a0, 0, 0, 0);
                a1 = __builtin_amdgcn_mfma_f32_16x16x32_f16(a, w0[1][8], a1, 0, 0, 0);
            }
#pragma unroll
            for (int r = 0; r < 4; ++r) { a0[r] += b0[0]; a1[r] += b0[1]; }
            float sA0 = __shfl_xor(hf ? a0[0] : a0[2], 8);
            float sA1 = __shfl_xor(hf ? a0[1] : a0[3], 8);
            float sB0 = __shfl_xor(hf ? a1[0] : a1[2], 8);
            float sB1 = __shfl_xor(hf ? a1[1] : a1[3], 8);
            unsigned hv = 0;
#pragma unroll
            for (int rr = 0; rr < 2; ++rr) {
                float sa = rr ? sA1 : sA0, sb = rr ? sB1 : sB0;
                float ig = hf ? sa : a0[rr];
                float fg = hf ? a0[2 + rr] : sa;
                float gg = hf ? sb : a1[rr];
                float og = hf ? a1[2 + rr] : sb;
                float c  = sigf(fg) * cs[mt][rr] + sigf(ig) * tanh_f(gg);
                cs[mt][rr] = c;
                float h  = sigf(og) * tanh_f(c);
                hv |= (unsigned)__builtin_bit_cast(u16, (f16_t)h) << (16 * rr);
            }
            PUB(gxw, mt, hv);
        }
    };
    auto GEMM1x = [&](float (&cs)[4][2], u16* gxw) {
#pragma unroll
        for (int mt = 0; mt < 4; ++mt) {
            f32x4 a0 = {}, a1 = {};
            const int arow = mt * 16 + lrow;
#pragma unroll
            for (int ks = 0; ks < 8; ++ks) {
                f16x8 a = *(const f16x8*)(h0b + arow * 512 + ((ks * 64 + lkg * 16) ^ aswz));
                a0 = __builtin_amdgcn_mfma_f32_16x16x32_f16(a, w1[0][ks], a0, 0, 0, 0);
                a1 = __builtin_amdgcn_mfma_f32_16x16x32_f16(a, w1[1][ks], a1, 0, 0, 0);
            }
#pragma unroll
            for (int ks = 0; ks < 8; ++ks) {
                f16x8 a = *(const f16x8*)(h1b + arow * 512 + ((ks * 64 + lkg * 16) ^ aswz));
                a0 = __builtin_amdgcn_mfma_f32_16x16x32_f16(a, w1[0][8 + ks], a0, 0, 0, 0);
                a1 = __builtin_amdgcn_mfma_f32_16x16x32_f16(a, w1[1][8 + ks], a1, 0, 0, 0);
            }
#pragma unroll
            for (int r = 0; r < 4; ++r) { a0[r] += b1[0]; a1[r] += b1[1]; }
            float sA0 = __shfl_xor(hf ? a0[0] : a0[2], 8);
            float sA1 = __shfl_xor(hf ? a0[1] : a0[3], 8);
            float sB0 = __shfl_xor(hf ? a1[0] : a1[2], 8);
            float sB1 = __shfl_xor(hf ? a1[1] : a1[3], 8);
            unsigned hv = 0;
#pragma unroll
            for (int rr = 0; rr < 2; ++rr) {
                float sa = rr ? sA1 : sA0, sb = rr ? sB1 : sB0;
                float ig = hf ? sa : a0[rr];
                float fg = hf ? a0[2 + rr] : sa;
                float gg = hf ? sb : a1[rr];
                float og = hf ? a1[2 + rr] : sb;
                float c  = sigf(fg) * cs[mt][rr] + sigf(ig) * tanh_f(gg);
                cs[mt][rr] = c;
                float h  = sigf(og) * tanh_f(c);
                hv |= (unsigned)__builtin_bit_cast(u16, (f16_t)h) << (16 * rr);
            }
            PUB(gxw, mt, hv);
        }
    };
    auto RELF = [&](unsigned val) {     // call only right after __syncthreads()
        if (tid == 0)
            asm volatile("global_store_dword %0, %1, off sc0 sc1"
                         :: "v"(fme), "v"(val) : "memory");
    };
    auto SPINF = [&](unsigned tgt) {
        if (wv == 0) {
            while (true) {
                unsigned v = tgt;
                if (lane < 8)
                    asm volatile("global_load_dword %0, %1, off sc0 sc1\n\t"
                                 "s_waitcnt vmcnt(0)"
                                 : "=v"(v) : "v"(f + lane) : "memory");
                bool ok = (lane >= 8) || (v >= tgt);
                if (__all(ok)) break;
                __builtin_amdgcn_s_sleep(1);
            }
        }
        __syncthreads();
    };
    auto FILL2 = [&](char* d0, const u16* s0, bool e0,
                     char* d1, const u16* s1, bool e1) {
        u32x4 q0[8], q1[8];
        const int row = tid & 63;
        const int base = (tid >> 6) * 2;
#pragma unroll
        for (int ss = 0; ss < 2; ++ss) {
            int s2 = base + ss;
            if (e0) {
                const char* sp = (const char*)s0 + s2 * 4096 + row * 64;
#pragma unroll
                for (int j = 0; j < 4; ++j)
                    asm volatile("global_load_dwordx4 %0, %1, off sc0 sc1"
                                 : "=&v"(q0[ss * 4 + j]) : "v"(sp + j * 16));
            }
            if (e1) {
                const char* sp = (const char*)s1 + s2 * 4096 + row * 64;
#pragma unroll
                for (int j = 0; j < 4; ++j)
                    asm volatile("global_load_dwordx4 %0, %1, off sc0 sc1"
                                 : "=&v"(q1[ss * 4 + j]) : "v"(sp + j * 16));
            }
        }
        asm volatile("s_waitcnt vmcnt(0)" ::: "memory");
        __builtin_amdgcn_sched_barrier(0);
        const int sw = (row & 7) << 4;
#pragma unroll
        for (int ss = 0; ss < 2; ++ss) {
            int s2 = base + ss;
            if (e0) {
#pragma unroll
                for (int j = 0; j < 4; ++j)
                    *(u32x4*)(d0 + row * 512 + ((s2 * 64 + j * 16) ^ sw)) = q0[ss * 4 + j];
            }
            if (e1) {
#pragma unroll
                for (int j = 0; j < 4; ++j)
                    *(u32x4*)(d1 + row * 512 + ((s2 * 64 + j * 16) ^ sw)) = q1[ss * 4 + j];
            }
        }
    };
    auto XLOAD = [&](int tt, float& v0, float& v1) {
        v0 = 0.f; v1 = 0.f;
        int i0 = tid, i1 = tid + 256;
        if (i0 < 320) { int row = i0 / 5, k = i0 - row * 5;
            v0 = x[((size_t)(r0 + row) * T_STEPS + tt) * IN_DIM + k]; }
        if (i1 < 320) { int row = i1 / 5, k = i1 - row * 5;
            v1 = x[((size_t)(r0 + row) * T_STEPS + tt) * IN_DIM + k]; }
    };
    auto XSTAGE = [&](float v0, float v1) {
        int i0 = tid, i1 = tid + 256;
        if (i0 < 320) { int row = i0 / 5, k = i0 - row * 5;
            *(u16*)(xbb + row * 64 + ((2 * k) ^ ((row & 3) << 4))) = __builtin_bit_cast(u16, (f16_t)v0); }
        if (i1 < 320) { int row = i1 / 5, k = i1 - row * 5;
            *(u16*)(xbb + row * 64 + ((2 * k) ^ ((row & 3) << 4))) = __builtin_bit_cast(u16, (f16_t)v1); }
    };
    auto FC = [&](int tIdx) {
        if (wv == 0 && sub < 4) {
            f32x4 acc = {};
            const int arow = sub * 16 + lrow;
#pragma unroll
            for (int ks = 0; ks < 8; ++ks) {
                f16x8 a  = *(const f16x8*)(h1b + arow * 512 + ((ks * 64 + lkg * 16) ^ aswz));
                f16x8 wb = *(const f16x8*)(wfcL + ks * 1024 + lane * 16);
                acc = __builtin_amdgcn_mfma_f32_16x16x32_f16(a, wb, acc, 0, 0, 0);
            }
            if (lrow == 0) {
#pragma unroll
                for (int r = 0; r < 4; ++r)
                    out[(size_t)(r0 + sub * 16 + lkg * 4 + r) * T_STEPS + tIdx] = acc[r] + fcb;
            }
        }
    };

#pragma unroll 1
    for (int t = 0; t < T_STEPS; ++t) {
        const int pc = t & 1, pp = (t - 1) & 1;

        float xv0, xv1;
        if (t + 1 < T_STEPS) { XLOAD(t + 1, xv0, xv1); } else { xv0 = 0.f; xv1 = 0.f; }

        // ---- C: GEMM0(t) [h0(t-1),x(t)] + GEMM1(t-1) [h0(t-1),h1(t-2)] ----
        GEMM0x(c0, gxr(0, pc));                   // pub h0(t)
        if (t > 0) GEMM1x(c1, gxr(1, pp));        // pub h1(t-1)
        __syncthreads();                          // vmcnt(0): pubs at coherence point
        RELF((unsigned)(t + 1));
        if (t + 1 < T_STEPS) XSTAGE(xv0, xv1);    // xb(t+1); ordered by SPIN's barrier

        // ---- S: spin all CUs' C(t); fill h0(t) + h1(t-1); FC(t-1) ----
        SPINF((unsigned)(t + 1));
        FILL2(h0b, gxr(0, pc), true,
              h1b, gxr(1, pp), t > 0);
        __syncthreads();                          // LDS fills visible
        if (t > 0) FC(t - 1);
    }

    // ---- epilogue: GEMM1(255), exchange h1(255), FC(255) ----
    GEMM1x(c1, gxr(1, 1));                        // pub h1(255), parity 255&1=1
    __syncthreads();
    RELF(257u);
    SPINF(257u);
    FILL2(h1b, gxr(1, 1), true, h1b, gxr(1, 1), false);
    __syncthreads();
    FC(255);
}

extern "C" void kernel_launch(void* const* d_in, const int* in_sizes, int n_in,
                              void* d_out, int out_size, void* d_ws, size_t ws_size,
                              hipStream_t stream)
{
    const float* x    = (const float*)d_in[0];
    const float* wih0 = (const float*)d_in[1];
    const float* whh0 = (const float*)d_in[2];
    const float* bih0 = (const float*)d_in[3];
    const float* bhh0 = (const float*)d_in[4];
    const float* wih1 = (const float*)d_in[5];
    const float* whh1 = (const float*)d_in[6];
    const float* bih1 = (const float*)d_in[7];
    const float* bhh1 = (const float*)d_in[8];
    const float* fcw  = (const float*)d_in[9];
    const float* fcb  = (const float*)d_in[10];

    u16* wsw      = (u16*)d_ws;
    float* biases = (float*)((char*)d_ws + WS_BIAS);
    u16* wsfc     = (u16*)((char*)d_ws + WS_FC);
    u16* gxbase   = (u16*)((char*)d_ws + WS_GX);
    unsigned* cnt = (unsigned*)((char*)d_ws + WS_CNT);

    prep_kernel<<<419, 256, 0, stream>>>(wih0, whh0, wih1, whh1,
                                         bih0, bhh0, bih1, bhh1, fcw,
                                         wsw, biases, wsfc, cnt);
    lstm_fused<<<NBLK, 256, 77824, stream>>>(x, wsw, biases, wsfc, fcb,
                                             (float*)d_out, gxbase, cnt);
}